// Round 3
// baseline (451.864 us; speedup 1.0000x reference)
//
#include <hip/hip_runtime.h>
#include <hip/hip_bf16.h>

typedef unsigned int uint;
typedef unsigned short ushort;

constexpr int Bn = 256, Sn = 512, Vn = 32000, Dn = 100, Hn = 75, Ln = 128;
constexpr int EW = 80;    // embW row stride (floats), cols 75..79 zero
constexpr int KP = 96;    // h_all row stride (f16) = MFMA K-pad (3 x 32)
constexpr int W2S = 80;   // w2p row stride (f16)

// workspace layout (float units)
constexpr size_t OFF_EMBW = 0;                          // 32000*80   = 2,560,000 f
constexpr size_t OFF_HALL = OFF_EMBW + (size_t)Vn*EW;   // 131072*96 f16 = 6,291,456 f
constexpr size_t OFF_W2P  = OFF_HALL + (size_t)Bn*Sn*KP/2; // 80*80 f16 = 3200 f
constexpr size_t OFF_WOH  = OFF_W2P + 3200;             // 80*96 f16  = 3840 f
constexpr size_t OFF_WFH  = OFF_WOH + 3840;             // 128*96 f16 = 6144 f

typedef __attribute__((ext_vector_type(2))) _Float16 half2_t;
typedef __attribute__((ext_vector_type(8))) _Float16 half8;
typedef __attribute__((ext_vector_type(4))) float floatx4;

__device__ __forceinline__ ushort f2h(float f){
    union { _Float16 h; ushort u; } v; v.h = (_Float16)f; return v.u;
}
__device__ __forceinline__ half2_t as_h2(uint u){
    union { uint u; half2_t h; } v; v.u = u; return v.h;
}
__device__ __forceinline__ float sigmoidf(float z){ return 1.f/(1.f + __expf(-z)); }

// ---------------------------------------------------------------------------
// Prep: W2 -> [80][80] f16 (pad 0), Wo -> [80][96] f16, Wfc -> [128][96] f16,
// zero h_all pad cols 80..95 (so k_out never reads garbage).
// ---------------------------------------------------------------------------
__global__ __launch_bounds__(256) void k_wprep(
    const float* __restrict__ W2, const float* __restrict__ Wo,
    const float* __restrict__ Wfc, ushort* __restrict__ w2p,
    ushort* __restrict__ woh, ushort* __restrict__ wfh, ushort* __restrict__ h_all)
{
    const int tid = blockIdx.x*256 + threadIdx.x;
    const int stride = gridDim.x*256;
    for (int i = tid; i < 80*W2S; i += stride){
        int r = i / W2S, k = i % W2S;
        w2p[i] = (r < Hn && k < Hn) ? f2h(W2[r*Hn + k]) : (ushort)0;
    }
    for (int i = tid; i < 80*KP; i += stride){
        int r = i / KP, k = i % KP;
        woh[i] = (r < Hn && k < Hn) ? f2h(Wo[r*Hn + k]) : (ushort)0;
    }
    for (int i = tid; i < Ln*KP; i += stride){
        int l = i / KP, k = i % KP;
        wfh[i] = (k < Hn) ? f2h(Wfc[l*Hn + k]) : (ushort)0;
    }
    // h_all[row][80..95] = 0  (8 uints per row)
    uint* hu = (uint*)h_all;
    for (int i = tid; i < Bn*Sn*8; i += stride){
        int row = i >> 3, c = i & 7;
        hu[(size_t)row*48 + 40 + c] = 0u;
    }
}

// ---------------------------------------------------------------------------
// embW[v][j] = sum_d emb[v][d]*W1[j][d] + b1[j] + b2[j], stride EW=80,
// cols 75..79 zero. One wave per 64 vocab rows; W1 via wave-uniform s_loads.
// ---------------------------------------------------------------------------
__global__ __launch_bounds__(64) void k_embproj(
    const float* __restrict__ emb, const float* __restrict__ W1,
    const float* __restrict__ b1, const float* __restrict__ b2,
    float* __restrict__ embW)
{
    const int lane = threadIdx.x;
    const int v = blockIdx.x*64 + lane;
    const float4* ev = (const float4*)(emb + (size_t)v*Dn);
    float e[Dn];
    #pragma unroll
    for (int q = 0; q < Dn/4; ++q){
        float4 x = ev[q];
        e[4*q] = x.x; e[4*q+1] = x.y; e[4*q+2] = x.z; e[4*q+3] = x.w;
    }
    __shared__ float s_out[64*EW];
    #pragma unroll 4
    for (int j = 0; j < Hn; ++j){
        float a0 = b1[j] + b2[j], a1 = 0.f, a2 = 0.f, a3 = 0.f;
        const float* w = W1 + j*Dn;              // uniform -> s_loads
        #pragma unroll
        for (int d = 0; d < Dn; d += 4){
            a0 += w[d]*e[d];     a1 += w[d+1]*e[d+1];
            a2 += w[d+2]*e[d+2]; a3 += w[d+3]*e[d+3];
        }
        s_out[lane*EW + j] = (a0+a1) + (a2+a3);
    }
    #pragma unroll
    for (int j = Hn; j < EW; ++j) s_out[lane*EW + j] = 0.f;
    __syncthreads();
    float* dst = embW + (size_t)blockIdx.x*64*EW;
    for (int i = lane; i < 64*EW; i += 64) dst[i] = s_out[i];
}

// ---------------------------------------------------------------------------
// Sequential scan: ONE WAVE per batch row. Lane L computes h[L] and h[64+L].
// r0-r2 post-mortem: step time ~995cy, VALUBusy 17.5% ~= exactly the 80
// fdot2 -- the other ~820cy was in-loop VMEM latency (per-step W2 reloads:
// VGPR 52 can't hold 80 weight uints; plus the token-dependent embW gather,
// L3 ~600-900cy). Fix is STRUCTURAL, not allocator-fighting:
//  (1) W2 lives in LDS at stride 176B (12L+4q bank spread: all 32 banks
//      covered -> minimal b128 conflict). 20 ds_read_b128/step on the LDS
//      pipe run parallel to the VALU chain; lgkmcnt is fine-grained.
//      asm volatile on the base defeats LICM (no 80-reg hoist -> no spill).
//  (2) xp (= embW[token] row) staged per 64-step chunk into an LDS double
//      buffer via 20x global_load_lds width-16 (global src IS per-lane ->
//      token gather legal; LDS dest linear). One __syncthreads per chunk is
//      the only vmcnt drain. In-loop xp reads: 2-deep prefetched ds_read.
// h broadcast: sigmoid -> f2h -> DPP quad_perm pack -> 40x readlane -> SGPR
// pairs feeding v_dot2_f32_f16 (correctness proven in r1/r2).
// ---------------------------------------------------------------------------
__global__ __attribute__((amdgpu_flat_work_group_size(64,64)))
__attribute__((amdgpu_waves_per_eu(1,1)))
void k_rnn(
    const int* __restrict__ X, const float* __restrict__ embW,
    const ushort* __restrict__ w2p, ushort* __restrict__ h_all)
{
    const int b = blockIdx.x;
    const int L = threadIdx.x;
    __shared__ int sX[Sn];                         // 2 KB
    __shared__ __align__(16) ushort w2a[80*88];    // 14 KB, stride 176B
    __shared__ __align__(16) float xpb[2][64*80];  // 40 KB xp double buffer

    for (int i = L; i < Sn; i += 64) sX[i] = X[b*Sn + i];
    {   // W2 f16-packed [80][40] uints -> LDS stride 44 uints (176B rows)
        const uint* src = (const uint*)w2p;
        uint* dst = (uint*)w2a;
        for (int i = L; i < 80*40; i += 64){
            int r = i / 40, c = i - r*40;
            dst[r*44 + c] = src[i];
        }
    }
    __syncthreads();

    // stage chunk c (64 steps x 320B) into xpb[c&1] via global_load_lds.
    // 16B chunk idx = k*64+L; row cs = idx/20, offset off = idx%20;
    // src = embW[tok]*320B + off*16B (16B aligned); LDS dst = buf + idx*16B.
    auto stage = [&](int c){
        float* buf = xpb[c & 1];
        const int base = c*64;
        #pragma unroll
        for (int k = 0; k < 20; ++k){
            int idx = k*64 + L;
            int cs  = idx / 20;
            int off = idx - cs*20;
            int tok = sX[base + cs];
            const float* src = embW + (size_t)tok*EW + off*4;
            __builtin_amdgcn_global_load_lds(
                (const __attribute__((address_space(1))) uint*)src,
                (__attribute__((address_space(3))) uint*)(buf + k*256),
                16, 0, 0);
        }
    };

    ushort* hout = h_all + (size_t)b*Sn*KP;
    uint hp[40];                                   // h pairs, SGPR-resident
    #pragma unroll
    for (int q = 0; q < 40; ++q) hp[q] = 0u;

    stage(0);
    for (int c = 0; c < 8; ++c){
        __syncthreads();                 // chunk c landed (vmcnt drain, 1/64 steps)
        if (c < 7) stage(c + 1);         // async stage into the other buffer
        const float* xp = xpb[c & 1];
        // xp prefetch pipeline (2 deep), addresses compile-known
        float x1c = xp[L];
        float x2c = (L < 16) ? xp[64 + L] : 0.f;
        float x1n = xp[80 + L];
        float x2n = (L < 16) ? xp[80 + 64 + L] : 0.f;
        #pragma unroll 4
        for (int t = 0; t < 64; ++t){
            int pf = (t + 2 < 64) ? t + 2 : 63;    // clamped slots never consumed
            float x1f = xp[pf*80 + L];
            float x2f = (L < 16) ? xp[pf*80 + 64 + L] : 0.f;
            // weight rows from LDS; opaque base defeats LICM/hoist-to-regs
            uint lb1 = (uint)L*176;
            uint lb2 = (uint)((L < 16) ? (64 + L) : 79)*176;
            asm volatile("" : "+v"(lb1), "+v"(lb2));
            const uint4* r1 = (const uint4*)((const char*)w2a + lb1);
            const uint4* r2 = (const uint4*)((const char*)w2a + lb2);
            float a0=x1c, a1=0.f, a2=0.f, a3=0.f;
            float c0=x2c, c1=0.f, c2=0.f, c3=0.f;
            #pragma unroll
            for (int q = 0; q < 10; ++q){
                uint4 wa = r1[q];
                uint4 wc = r2[q];
                a0 = __builtin_amdgcn_fdot2(as_h2(wa.x), as_h2(hp[4*q+0]), a0, false);
                a1 = __builtin_amdgcn_fdot2(as_h2(wa.y), as_h2(hp[4*q+1]), a1, false);
                a2 = __builtin_amdgcn_fdot2(as_h2(wa.z), as_h2(hp[4*q+2]), a2, false);
                a3 = __builtin_amdgcn_fdot2(as_h2(wa.w), as_h2(hp[4*q+3]), a3, false);
                c0 = __builtin_amdgcn_fdot2(as_h2(wc.x), as_h2(hp[4*q+0]), c0, false);
                c1 = __builtin_amdgcn_fdot2(as_h2(wc.y), as_h2(hp[4*q+1]), c1, false);
                c2 = __builtin_amdgcn_fdot2(as_h2(wc.z), as_h2(hp[4*q+2]), c2, false);
                c3 = __builtin_amdgcn_fdot2(as_h2(wc.w), as_h2(hp[4*q+3]), c3, false);
            }
            float h1 = sigmoidf((a0+a1)+(a2+a3));
            float h2 = sigmoidf((c0+c1)+(c2+c3));
            if (L >= 11) h2 = 0.f;                 // j = 75..79 pad and beyond
            ushort u1 = f2h(h1);
            ushort u2 = f2h(h2);
            int s = c*64 + t;
            hout[(size_t)s*KP + L] = u1;
            if (L < 16) hout[(size_t)s*KP + 64 + L] = u2;
            // pack adjacent lanes' f16 into pairs via DPP quad_perm [1,0,3,2]
            uint v1 = u1, v2 = u2;
            uint pr1 = (uint)__builtin_amdgcn_update_dpp(0, (int)v1, 0xB1, 0xF, 0xF, true);
            uint pr2 = (uint)__builtin_amdgcn_update_dpp(0, (int)v2, 0xB1, 0xF, 0xF, true);
            uint q1 = v1 | (pr1 << 16);
            uint q2 = v2 | (pr2 << 16);
            #pragma unroll
            for (int q = 0; q < 32; ++q) hp[q] = (uint)__builtin_amdgcn_readlane((int)q1, 2*q);
            #pragma unroll
            for (int q = 0; q < 8; ++q)  hp[32+q] = (uint)__builtin_amdgcn_readlane((int)q2, 2*q);
            x1c = x1n; x2c = x2n; x1n = x1f; x2n = x2f;
        }
    }
}

// ---------------------------------------------------------------------------
// Epilogue GEMM via MFMA 16x16x32 f16. Per block: 4 waves x 16 rows.
// Phase1: Z = H(16x96)@Wo^T + bo -> sigmoid -> O f16 in LDS (stride 104);
// Phase2: OUT = O@Wfc^T + bfc.
// C/D frag: col=lane&15, row=(lane>>4)*4+reg (m89-verified, dtype-indep).
// ---------------------------------------------------------------------------
__global__ __launch_bounds__(256) void k_out(
    const ushort* __restrict__ h_all, const ushort* __restrict__ woh,
    const ushort* __restrict__ wfh, const float* __restrict__ bo,
    const float* __restrict__ bfc, float* __restrict__ out)
{
    const int lane = threadIdx.x & 63;
    const int w    = threadIdx.x >> 6;
    const size_t r0 = (size_t)blockIdx.x*64 + w*16;
    const int m = lane & 15;
    const int g = lane >> 4;
    __shared__ __align__(16) ushort o_lds[4][16*104];
    ushort* ot = o_lds[w];
    // zero O pad cols 80..95 (read by k-step 2); wave-local, no barrier needed
    for (int i = lane; i < 128; i += 64){
        int row = i >> 3, cw = i & 7;
        *(uint*)&ot[row*104 + 80 + cw*2] = 0u;
    }
    // ---- Phase 1: Z = H @ Wo^T ----
    floatx4 acc1[5] = {};
    const ushort* hbase = h_all + r0*KP;
    #pragma unroll
    for (int ks = 0; ks < 3; ++ks){
        half8 a = *(const half8*)(hbase + (size_t)m*KP + ks*32 + g*8);
        #pragma unroll
        for (int t = 0; t < 5; ++t){
            half8 bt = *(const half8*)(woh + (16*t + m)*KP + ks*32 + g*8);
            acc1[t] = __builtin_amdgcn_mfma_f32_16x16x32_f16(a, bt, acc1[t], 0, 0, 0);
        }
    }
    // ---- bo + sigmoid -> O (f16, C layout) ----
    #pragma unroll
    for (int t = 0; t < 5; ++t){
        int n = 16*t + m;
        float bias = (n < Hn) ? bo[n] : 0.f;
        #pragma unroll
        for (int r = 0; r < 4; ++r){
            int row = g*4 + r;
            float o = sigmoidf(acc1[t][r] + bias);
            if (n >= Hn) o = 0.f;              // pad rows -> z=0 -> 0.5; kill
            ot[row*104 + n] = f2h(o);
        }
    }
    // wave-local LDS RAW: in-order DS pipe within a wave; no barrier
    // ---- Phase 2: OUT = O @ Wfc^T ----
    floatx4 acc2[8] = {};
    #pragma unroll
    for (int ks = 0; ks < 3; ++ks){
        half8 a = *(const half8*)(ot + m*104 + ks*32 + g*8);
        #pragma unroll
        for (int t = 0; t < 8; ++t){
            half8 bt = *(const half8*)(wfh + (16*t + m)*KP + ks*32 + g*8);
            acc2[t] = __builtin_amdgcn_mfma_f32_16x16x32_f16(a, bt, acc2[t], 0, 0, 0);
        }
    }
    // ---- bfc + store ----
    float* orow = out + r0*Ln;
    #pragma unroll
    for (int t = 0; t < 8; ++t){
        float bias = bfc[16*t + m];
        #pragma unroll
        for (int r = 0; r < 4; ++r){
            int row = g*4 + r;
            orow[(size_t)row*Ln + 16*t + m] = acc2[t][r] + bias;
        }
    }
}

extern "C" void kernel_launch(void* const* d_in, const int* in_sizes, int n_in,
                              void* d_out, int out_size, void* d_ws, size_t ws_size,
                              hipStream_t stream)
{
    const int*   X   = (const int*)d_in[0];
    const float* emb = (const float*)d_in[1];
    const float* W1  = (const float*)d_in[2];
    const float* b1  = (const float*)d_in[3];
    const float* W2  = (const float*)d_in[4];
    const float* b2  = (const float*)d_in[5];
    const float* Wo  = (const float*)d_in[6];
    const float* bo  = (const float*)d_in[7];
    const float* Wfc = (const float*)d_in[8];
    const float* bfc = (const float*)d_in[9];
    float* out = (float*)d_out;
    float* ws  = (float*)d_ws;

    float*  embW = ws + OFF_EMBW;
    ushort* hall = (ushort*)(ws + OFF_HALL);
    ushort* w2p  = (ushort*)(ws + OFF_W2P);
    ushort* woh  = (ushort*)(ws + OFF_WOH);
    ushort* wfh  = (ushort*)(ws + OFF_WFH);

    k_wprep<<<dim3(512), dim3(256), 0, stream>>>(W2, Wo, Wfc, w2p, woh, wfh, hall);
    k_embproj<<<dim3(Vn/64), dim3(64), 0, stream>>>(emb, W1, b1, b2, embW);
    k_rnn<<<dim3(Bn), dim3(64), 0, stream>>>(X, embW, w2p, hall);
    k_out<<<dim3((Bn*Sn)/64), dim3(256), 0, stream>>>(hall, woh, wfh, bo, bfc, out);
}

// Round 4
// 370.929 us; speedup vs baseline: 1.2182x; 1.2182x over previous
//
#include <hip/hip_runtime.h>
#include <hip/hip_bf16.h>

typedef unsigned int uint;
typedef unsigned short ushort;

constexpr int Bn = 256, Sn = 512, Vn = 32000, Dn = 100, Hn = 75, Ln = 128;
constexpr int EW = 80;    // embW row stride (floats), cols 75..79 zero
constexpr int KP = 96;    // h_all row stride (f16) = MFMA K-pad (3 x 32)
constexpr int W2S = 80;   // w2p row stride (f16)

// workspace layout (float units)
constexpr size_t OFF_EMBW = 0;                          // 32000*80   = 2,560,000 f
constexpr size_t OFF_HALL = OFF_EMBW + (size_t)Vn*EW;   // 131072*96 f16 = 6,291,456 f
constexpr size_t OFF_W2P  = OFF_HALL + (size_t)Bn*Sn*KP/2; // 80*80 f16 = 3200 f
constexpr size_t OFF_WOH  = OFF_W2P + 3200;             // 80*96 f16  = 3840 f
constexpr size_t OFF_WFH  = OFF_WOH + 3840;             // 128*96 f16 = 6144 f

typedef __attribute__((ext_vector_type(2))) _Float16 half2_t;
typedef __attribute__((ext_vector_type(8))) _Float16 half8;
typedef __attribute__((ext_vector_type(4))) float floatx4;

__device__ __forceinline__ ushort f2h(float f){
    union { _Float16 h; ushort u; } v; v.h = (_Float16)f; return v.u;
}
__device__ __forceinline__ float sigmoidf(float z){ return 1.f/(1.f + __expf(-z)); }

// ---------------------------------------------------------------------------
// Prep: W2 -> [80][80] f16 (pad 0), Wo -> [80][96] f16, Wfc -> [128][96] f16,
// zero h_all pad cols 80..95 (so k_out never reads garbage).
// ---------------------------------------------------------------------------
__global__ __launch_bounds__(256) void k_wprep(
    const float* __restrict__ W2, const float* __restrict__ Wo,
    const float* __restrict__ Wfc, ushort* __restrict__ w2p,
    ushort* __restrict__ woh, ushort* __restrict__ wfh, ushort* __restrict__ h_all)
{
    const int tid = blockIdx.x*256 + threadIdx.x;
    const int stride = gridDim.x*256;
    for (int i = tid; i < 80*W2S; i += stride){
        int r = i / W2S, k = i % W2S;
        w2p[i] = (r < Hn && k < Hn) ? f2h(W2[r*Hn + k]) : (ushort)0;
    }
    for (int i = tid; i < 80*KP; i += stride){
        int r = i / KP, k = i % KP;
        woh[i] = (r < Hn && k < Hn) ? f2h(Wo[r*Hn + k]) : (ushort)0;
    }
    for (int i = tid; i < Ln*KP; i += stride){
        int l = i / KP, k = i % KP;
        wfh[i] = (k < Hn) ? f2h(Wfc[l*Hn + k]) : (ushort)0;
    }
    // h_all[row][80..95] = 0  (8 uints per row)
    uint* hu = (uint*)h_all;
    for (int i = tid; i < Bn*Sn*8; i += stride){
        int row = i >> 3, c = i & 7;
        hu[(size_t)row*48 + 40 + c] = 0u;
    }
}

// ---------------------------------------------------------------------------
// embW[v][j] = sum_d emb[v][d]*W1[j][d] + b1[j] + b2[j], stride EW=80,
// cols 75..79 zero. One wave per 64 vocab rows.
// waves_per_eu(1,1): e[100] needs ~100 VGPRs; default occupancy heuristic
// would cap regs and spill e[] to scratch (same allocator trap as k_rnn r1/r2).
// ---------------------------------------------------------------------------
__global__ __attribute__((amdgpu_flat_work_group_size(64,64)))
__attribute__((amdgpu_waves_per_eu(1,1)))
void k_embproj(
    const float* __restrict__ emb, const float* __restrict__ W1,
    const float* __restrict__ b1, const float* __restrict__ b2,
    float* __restrict__ embW)
{
    const int lane = threadIdx.x;
    const int v = blockIdx.x*64 + lane;
    const float4* ev = (const float4*)(emb + (size_t)v*Dn);
    float e[Dn];
    #pragma unroll
    for (int q = 0; q < Dn/4; ++q){
        float4 x = ev[q];
        e[4*q] = x.x; e[4*q+1] = x.y; e[4*q+2] = x.z; e[4*q+3] = x.w;
    }
    __shared__ float s_out[64*EW];
    #pragma unroll 4
    for (int j = 0; j < Hn; ++j){
        float a0 = b1[j] + b2[j], a1 = 0.f, a2 = 0.f, a3 = 0.f;
        const float* w = W1 + j*Dn;              // uniform -> s_loads
        #pragma unroll
        for (int d = 0; d < Dn; d += 4){
            a0 += w[d]*e[d];     a1 += w[d+1]*e[d+1];
            a2 += w[d+2]*e[d+2]; a3 += w[d+3]*e[d+3];
        }
        s_out[lane*EW + j] = (a0+a1) + (a2+a3);
    }
    #pragma unroll
    for (int j = Hn; j < EW; ++j) s_out[lane*EW + j] = 0.f;
    __syncthreads();
    float* dst = embW + (size_t)blockIdx.x*64*EW;
    for (int i = lane; i < 64*EW; i += 64) dst[i] = s_out[i];
}

// ---------------------------------------------------------------------------
// Sequential scan: ONE WAVE per batch row. MFMA-based recurrence.
// r0-r3 post-mortem: the fdot2 scheme needs 80 VGPRs/lane of W2 -- allocator
// refused (VGPR 52-72, per-step VMEM reloads ~820cy stall) and LDS-resident
// weights cost ~360cy of LDS latency+pipe on the serial chain (r3, 263us).
// MFMA spreads W2 across lanes: 15 B-fragments (16x16x32 f16) = 60 VGPRs
// TOTAL, loaded once.  y = W2 @ h via D = A*B with A[m][k] = h[k] (all rows
// identical): lane reads A-frag by g=lane>>4 only.  Extraction is LANE-LOCAL:
// C/D col=lane&15,row=(lane>>4)*4+r (k_out-verified) => y[L] = acc[L>>4][0].
// h broadcast: 2 ds_write_b16 + 3 ds_read_b128 (4 distinct 16B segments,
// bank-conflict-free broadcast); in-wave DS program order, no barrier.
// B-frag k>=80 garbage is harmless: A (hlds[80..95]) is zero there.
// xp: direct global 3-deep VGPR prefetch (r0-proven; no LDS aliasing).
// ---------------------------------------------------------------------------
__global__ __attribute__((amdgpu_flat_work_group_size(64,64)))
__attribute__((amdgpu_waves_per_eu(1,1)))
void k_rnn(
    const int* __restrict__ X, const float* __restrict__ embW,
    const ushort* __restrict__ w2p, ushort* __restrict__ h_all)
{
    const int b = blockIdx.x;
    const int L = threadIdx.x;
    const int m = L & 15;
    const int g = L >> 4;
    __shared__ int sX[Sn];                       // 2 KB
    __shared__ __align__(16) ushort hlds[96];    // h_t, f16, cols 80..95 = 0

    for (int i = L; i < Sn; i += 64) sX[i] = X[b*Sn + i];
    if (L < 48) ((uint*)hlds)[L] = 0u;           // h_{-1} = 0, pad = 0

    // B-fragments: lane holds W2[n=16t+m][k0..k0+7], k0 = ks*32+g*8.
    // w2p row stride 160B, k0*2 multiple of 16 -> 16B-aligned half8 loads.
    half8 bfr[5][3];
    #pragma unroll
    for (int t = 0; t < 5; ++t){
        #pragma unroll
        for (int ks = 0; ks < 3; ++ks){
            int k0 = ks*32 + g*8;
            half8 bv = {};
            if (k0 < 80) bv = *(const half8*)(w2p + (size_t)(16*t + m)*W2S + k0);
            bfr[t][ks] = bv;                     // k0>=80: A is zero there anyway
        }
    }
    __syncthreads();                             // single wave: trivial

    ushort* hout = h_all + (size_t)b*Sn*KP;
    // xp prefetch pipeline (3 deep): x1 = embW[tok][L], x2 = embW[tok][64+L]
    float x1c, x2c, x1n, x2n, x1m, x2m;
    {
        int t0 = sX[0], t1 = sX[1], t2 = sX[2];
        x1c = embW[(size_t)t0*EW + L];
        x2c = (L < 16) ? embW[(size_t)t0*EW + 64 + L] : 0.f;
        x1n = embW[(size_t)t1*EW + L];
        x2n = (L < 16) ? embW[(size_t)t1*EW + 64 + L] : 0.f;
        x1m = embW[(size_t)t2*EW + L];
        x2m = (L < 16) ? embW[(size_t)t2*EW + 64 + L] : 0.f;
    }
    const floatx4 zero4 = {};

    for (int s = 0; s < Sn; ++s){
        // issue xp gather 3 ahead (consumed at s+3)
        int tok = sX[(s+3 < Sn) ? s+3 : Sn-1];
        float x1f = embW[(size_t)tok*EW + L];
        float x2f = (L < 16) ? embW[(size_t)tok*EW + 64 + L] : 0.f;

        // A-fragments: broadcast read of h_t (by g only; 4 distinct 16B segs)
        half8 af0 = *(const half8*)((const char*)hlds + 0*64 + g*16);
        half8 af1 = *(const half8*)((const char*)hlds + 1*64 + g*16);
        half8 af2 = *(const half8*)((const char*)hlds + 2*64 + g*16);

        // y = W2 @ h : 5 output tiles x 3 K-steps
        floatx4 acc0, acc1, acc2, acc3, acc4;
        acc0 = __builtin_amdgcn_mfma_f32_16x16x32_f16(af0, bfr[0][0], zero4, 0,0,0);
        acc1 = __builtin_amdgcn_mfma_f32_16x16x32_f16(af0, bfr[1][0], zero4, 0,0,0);
        acc2 = __builtin_amdgcn_mfma_f32_16x16x32_f16(af0, bfr[2][0], zero4, 0,0,0);
        acc3 = __builtin_amdgcn_mfma_f32_16x16x32_f16(af0, bfr[3][0], zero4, 0,0,0);
        acc4 = __builtin_amdgcn_mfma_f32_16x16x32_f16(af0, bfr[4][0], zero4, 0,0,0);
        acc0 = __builtin_amdgcn_mfma_f32_16x16x32_f16(af1, bfr[0][1], acc0, 0,0,0);
        acc1 = __builtin_amdgcn_mfma_f32_16x16x32_f16(af1, bfr[1][1], acc1, 0,0,0);
        acc2 = __builtin_amdgcn_mfma_f32_16x16x32_f16(af1, bfr[2][1], acc2, 0,0,0);
        acc3 = __builtin_amdgcn_mfma_f32_16x16x32_f16(af1, bfr[3][1], acc3, 0,0,0);
        acc4 = __builtin_amdgcn_mfma_f32_16x16x32_f16(af1, bfr[4][1], acc4, 0,0,0);
        acc0 = __builtin_amdgcn_mfma_f32_16x16x32_f16(af2, bfr[0][2], acc0, 0,0,0);
        acc1 = __builtin_amdgcn_mfma_f32_16x16x32_f16(af2, bfr[1][2], acc1, 0,0,0);
        acc2 = __builtin_amdgcn_mfma_f32_16x16x32_f16(af2, bfr[2][2], acc2, 0,0,0);
        acc3 = __builtin_amdgcn_mfma_f32_16x16x32_f16(af2, bfr[3][2], acc3, 0,0,0);
        acc4 = __builtin_amdgcn_mfma_f32_16x16x32_f16(af2, bfr[4][2], acc4, 0,0,0);

        // lane-local extraction: y[L] = acc[L>>4][0]; y[64+L] = acc4[0] (L<16)
        float y1 = (L < 32) ? ((L < 16) ? acc0[0] : acc1[0])
                            : ((L < 48) ? acc2[0] : acc3[0]);
        float y2 = acc4[0];

        float h1 = sigmoidf(y1 + x1c);
        float h2 = sigmoidf(y2 + x2c);
        if (L >= 11) h2 = 0.f;                   // cols 75..79 pad -> 0
        ushort u1 = f2h(h1);
        ushort u2 = f2h(h2);
        hout[(size_t)s*KP + L] = u1;
        hlds[L] = u1;                            // h_{t+1} into LDS (in-order DS)
        if (L < 16){
            hout[(size_t)s*KP + 64 + L] = u2;
            hlds[64 + L] = u2;                   // keeps hlds[75..79] = 0
        }
        x1c = x1n; x2c = x2n; x1n = x1m; x2n = x2m; x1m = x1f; x2m = x2f;
    }
}

// ---------------------------------------------------------------------------
// Epilogue GEMM via MFMA 16x16x32 f16. Per block: 4 waves x 16 rows.
// Phase1: Z = H(16x96)@Wo^T + bo -> sigmoid -> O f16 in LDS (stride 104);
// Phase2: OUT = O@Wfc^T + bfc.
// C/D frag: col=lane&15, row=(lane>>4)*4+reg (m89-verified, dtype-indep).
// ---------------------------------------------------------------------------
__global__ __launch_bounds__(256) void k_out(
    const ushort* __restrict__ h_all, const ushort* __restrict__ woh,
    const ushort* __restrict__ wfh, const float* __restrict__ bo,
    const float* __restrict__ bfc, float* __restrict__ out)
{
    const int lane = threadIdx.x & 63;
    const int w    = threadIdx.x >> 6;
    const size_t r0 = (size_t)blockIdx.x*64 + w*16;
    const int m = lane & 15;
    const int g = lane >> 4;
    __shared__ __align__(16) ushort o_lds[4][16*104];
    ushort* ot = o_lds[w];
    // zero O pad cols 80..95 (read by k-step 2); wave-local, no barrier needed
    for (int i = lane; i < 128; i += 64){
        int row = i >> 3, cw = i & 7;
        *(uint*)&ot[row*104 + 80 + cw*2] = 0u;
    }
    // ---- Phase 1: Z = H @ Wo^T ----
    floatx4 acc1[5] = {};
    const ushort* hbase = h_all + r0*KP;
    #pragma unroll
    for (int ks = 0; ks < 3; ++ks){
        half8 a = *(const half8*)(hbase + (size_t)m*KP + ks*32 + g*8);
        #pragma unroll
        for (int t = 0; t < 5; ++t){
            half8 bt = *(const half8*)(woh + (16*t + m)*KP + ks*32 + g*8);
            acc1[t] = __builtin_amdgcn_mfma_f32_16x16x32_f16(a, bt, acc1[t], 0, 0, 0);
        }
    }
    // ---- bo + sigmoid -> O (f16, C layout) ----
    #pragma unroll
    for (int t = 0; t < 5; ++t){
        int n = 16*t + m;
        float bias = (n < Hn) ? bo[n] : 0.f;
        #pragma unroll
        for (int r = 0; r < 4; ++r){
            int row = g*4 + r;
            float o = sigmoidf(acc1[t][r] + bias);
            if (n >= Hn) o = 0.f;              // pad rows -> z=0 -> 0.5; kill
            ot[row*104 + n] = f2h(o);
        }
    }
    // wave-local LDS RAW: in-order DS pipe within a wave; no barrier
    // ---- Phase 2: OUT = O @ Wfc^T ----
    floatx4 acc2[8] = {};
    #pragma unroll
    for (int ks = 0; ks < 3; ++ks){
        half8 a = *(const half8*)(ot + m*104 + ks*32 + g*8);
        #pragma unroll
        for (int t = 0; t < 8; ++t){
            half8 bt = *(const half8*)(wfh + (16*t + m)*KP + ks*32 + g*8);
            acc2[t] = __builtin_amdgcn_mfma_f32_16x16x32_f16(a, bt, acc2[t], 0, 0, 0);
        }
    }
    // ---- bfc + store ----
    float* orow = out + r0*Ln;
    #pragma unroll
    for (int t = 0; t < 8; ++t){
        float bias = bfc[16*t + m];
        #pragma unroll
        for (int r = 0; r < 4; ++r){
            int row = g*4 + r;
            orow[(size_t)row*Ln + 16*t + m] = acc2[t][r] + bias;
        }
    }
}

extern "C" void kernel_launch(void* const* d_in, const int* in_sizes, int n_in,
                              void* d_out, int out_size, void* d_ws, size_t ws_size,
                              hipStream_t stream)
{
    const int*   X   = (const int*)d_in[0];
    const float* emb = (const float*)d_in[1];
    const float* W1  = (const float*)d_in[2];
    const float* b1  = (const float*)d_in[3];
    const float* W2  = (const float*)d_in[4];
    const float* b2  = (const float*)d_in[5];
    const float* Wo  = (const float*)d_in[6];
    const float* bo  = (const float*)d_in[7];
    const float* Wfc = (const float*)d_in[8];
    const float* bfc = (const float*)d_in[9];
    float* out = (float*)d_out;
    float* ws  = (float*)d_ws;

    float*  embW = ws + OFF_EMBW;
    ushort* hall = (ushort*)(ws + OFF_HALL);
    ushort* w2p  = (ushort*)(ws + OFF_W2P);
    ushort* woh  = (ushort*)(ws + OFF_WOH);
    ushort* wfh  = (ushort*)(ws + OFF_WFH);

    k_wprep<<<dim3(512), dim3(256), 0, stream>>>(W2, Wo, Wfc, w2p, woh, wfh, hall);
    k_embproj<<<dim3(Vn/64), dim3(64), 0, stream>>>(emb, W1, b1, b2, embW);
    k_rnn<<<dim3(Bn), dim3(64), 0, stream>>>(X, embW, w2p, hall);
    k_out<<<dim3((Bn*Sn)/64), dim3(256), 0, stream>>>(hall, woh, wfh, bo, bfc, out);
}

// Round 5
// 367.582 us; speedup vs baseline: 1.2293x; 1.0091x over previous
//
#include <hip/hip_runtime.h>
#include <hip/hip_bf16.h>

typedef unsigned int uint;
typedef unsigned short ushort;

constexpr int Bn = 256, Sn = 512, Vn = 32000, Dn = 100, Hn = 75, Ln = 128;
constexpr int EW = 80;    // embW row stride (floats), cols 75..79 zero
constexpr int KP = 96;    // h_all row stride (f16) = MFMA K-pad (3 x 32)
constexpr int W2S = 80;   // w2p row stride (f16)

// workspace layout (float units)
constexpr size_t OFF_EMBW = 0;                          // 32000*80   = 2,560,000 f
constexpr size_t OFF_HALL = OFF_EMBW + (size_t)Vn*EW;   // 131072*96 f16 = 6,291,456 f
constexpr size_t OFF_W2P  = OFF_HALL + (size_t)Bn*Sn*KP/2; // 80*80 f16 = 3200 f
constexpr size_t OFF_WOH  = OFF_W2P + 3200;             // 80*96 f16  = 3840 f
constexpr size_t OFF_WFH  = OFF_WOH + 3840;             // 128*96 f16 = 6144 f

typedef __attribute__((ext_vector_type(2))) _Float16 half2_t;
typedef __attribute__((ext_vector_type(8))) _Float16 half8;
typedef __attribute__((ext_vector_type(4))) float floatx4;

__device__ __forceinline__ ushort f2h(float f){
    union { _Float16 h; ushort u; } v; v.h = (_Float16)f; return v.u;
}
__device__ __forceinline__ half8 as_h8(uint4 u){
    union { uint4 u; half8 h; } v; v.u = u; return v.h;
}
__device__ __forceinline__ float sigmoidf(float z){
    return __builtin_amdgcn_rcpf(1.f + __expf(-z));
}

// ---------------------------------------------------------------------------
// Prep: W2 -> [80][80] f16 (pad 0), Wo -> [80][96] f16, Wfc -> [128][96] f16,
// zero h_all pad cols 80..95 (so k_out never reads garbage).
// ---------------------------------------------------------------------------
__global__ __launch_bounds__(256) void k_wprep(
    const float* __restrict__ W2, const float* __restrict__ Wo,
    const float* __restrict__ Wfc, ushort* __restrict__ w2p,
    ushort* __restrict__ woh, ushort* __restrict__ wfh, ushort* __restrict__ h_all)
{
    const int tid = blockIdx.x*256 + threadIdx.x;
    const int stride = gridDim.x*256;
    for (int i = tid; i < 80*W2S; i += stride){
        int r = i / W2S, k = i % W2S;
        w2p[i] = (r < Hn && k < Hn) ? f2h(W2[r*Hn + k]) : (ushort)0;
    }
    for (int i = tid; i < 80*KP; i += stride){
        int r = i / KP, k = i % KP;
        woh[i] = (r < Hn && k < Hn) ? f2h(Wo[r*Hn + k]) : (ushort)0;
    }
    for (int i = tid; i < Ln*KP; i += stride){
        int l = i / KP, k = i % KP;
        wfh[i] = (k < Hn) ? f2h(Wfc[l*Hn + k]) : (ushort)0;
    }
    // h_all[row][80..95] = 0  (8 uints per row)
    uint* hu = (uint*)h_all;
    for (int i = tid; i < Bn*Sn*8; i += stride){
        int row = i >> 3, c = i & 7;
        hu[(size_t)row*48 + 40 + c] = 0u;
    }
}

// ---------------------------------------------------------------------------
// embW[v][j] = sum_d emb[v][d]*W1[j][d] + b1[j] + b2[j], stride EW=80,
// cols 75..79 zero. One wave per 64 vocab rows.
// waves_per_eu(1,1): e[100] needs ~100 VGPRs; default occupancy heuristic
// would cap regs and spill e[] to scratch.
// ---------------------------------------------------------------------------
__global__ __attribute__((amdgpu_flat_work_group_size(64,64)))
__attribute__((amdgpu_waves_per_eu(1,1)))
void k_embproj(
    const float* __restrict__ emb, const float* __restrict__ W1,
    const float* __restrict__ b1, const float* __restrict__ b2,
    float* __restrict__ embW)
{
    const int lane = threadIdx.x;
    const int v = blockIdx.x*64 + lane;
    const float4* ev = (const float4*)(emb + (size_t)v*Dn);
    float e[Dn];
    #pragma unroll
    for (int q = 0; q < Dn/4; ++q){
        float4 x = ev[q];
        e[4*q] = x.x; e[4*q+1] = x.y; e[4*q+2] = x.z; e[4*q+3] = x.w;
    }
    __shared__ float s_out[64*EW];
    #pragma unroll 4
    for (int j = 0; j < Hn; ++j){
        float a0 = b1[j] + b2[j], a1 = 0.f, a2 = 0.f, a3 = 0.f;
        const float* w = W1 + j*Dn;              // uniform -> s_loads
        #pragma unroll
        for (int d = 0; d < Dn; d += 4){
            a0 += w[d]*e[d];     a1 += w[d+1]*e[d+1];
            a2 += w[d+2]*e[d+2]; a3 += w[d+3]*e[d+3];
        }
        s_out[lane*EW + j] = (a0+a1) + (a2+a3);
    }
    #pragma unroll
    for (int j = Hn; j < EW; ++j) s_out[lane*EW + j] = 0.f;
    __syncthreads();
    float* dst = embW + (size_t)blockIdx.x*64*EW;
    for (int i = lane; i < 64*EW; i += 64) dst[i] = s_out[i];
}

// ---------------------------------------------------------------------------
// Sequential scan: ONE WAVE per batch row. MFMA recurrence (r4, 182.7us).
// r4 post-mortem: 857cy/step, MFMA issue 57cy + VALU 70cy -> ~730cy stall.
// Biggest serial piece: the hlds ds_write -> ds_read_b128 round-trip
// (~240-260cy: write completion + read latency, m117 ~120cy/op).
// r5 fix: rebuild A-fragments IN REGISTERS via ds_bpermute -- the A-frag is
// a gather of 8 consecutive lanes' h: DPP quad_perm pairs adjacent lanes'
// f16 (q1/q2 valid on even lanes), then 12 independent ds_bpermute_b32
// (af0/af2: pair j from src lane 2*(4g+j) -> addr 32g+8j; af1: +128B).
// One LDS-pipe pass (~130cy, overlapped) replaces the double pass; hlds gone.
// af2 k=80..95 stays zero: src lanes 16..30 have u2=0 (L>=11 zeroing).
// Extraction lane-local: y[L]=acc_g[0] (C/D col=lane&15,row=(lane>>4)*4+r).
// sigmoid: v_rcp instead of precise-division sequence.
// ---------------------------------------------------------------------------
__global__ __attribute__((amdgpu_flat_work_group_size(64,64)))
__attribute__((amdgpu_waves_per_eu(1,1)))
void k_rnn(
    const int* __restrict__ X, const float* __restrict__ embW,
    const ushort* __restrict__ w2p, ushort* __restrict__ h_all)
{
    const int b = blockIdx.x;
    const int L = threadIdx.x;
    const int m = L & 15;
    const int g = L >> 4;
    __shared__ int sX[Sn];                       // 2 KB (only LDS object)

    for (int i = L; i < Sn; i += 64) sX[i] = X[b*Sn + i];

    // B-fragments: lane holds W2[n=16t+m][k0..k0+7], k0 = ks*32+g*8.
    half8 bfr[5][3];
    #pragma unroll
    for (int t = 0; t < 5; ++t){
        #pragma unroll
        for (int ks = 0; ks < 3; ++ks){
            int k0 = ks*32 + g*8;
            half8 bv = {};
            if (k0 < 80) bv = *(const half8*)(w2p + (size_t)(16*t + m)*W2S + k0);
            bfr[t][ks] = bv;                     // k0>=80: A is zero there anyway
        }
    }
    __syncthreads();                             // single wave: trivial

    // bpermute byte-addresses (loop-invariant):
    // af0/af2 pair j <- src lane 2*(4g+j)  -> addr 32g+8j
    // af1       pair j <- src lane 2*(16+4g+j) -> addr 32g+8j+128
    int va0 = 32*g,      va1 = 32*g + 8,  va2 = 32*g + 16, va3 = 32*g + 24;
    int vb0 = va0 + 128, vb1 = va1 + 128, vb2 = va2 + 128, vb3 = va3 + 128;

    ushort* hout = h_all + (size_t)b*Sn*KP;
    // xp prefetch pipeline (3 deep): x1 = embW[tok][L], x2 = embW[tok][64+L]
    float x1c, x2c, x1n, x2n, x1m, x2m;
    {
        int t0 = sX[0], t1 = sX[1], t2 = sX[2];
        x1c = embW[(size_t)t0*EW + L];
        x2c = (L < 16) ? embW[(size_t)t0*EW + 64 + L] : 0.f;
        x1n = embW[(size_t)t1*EW + L];
        x2n = (L < 16) ? embW[(size_t)t1*EW + 64 + L] : 0.f;
        x1m = embW[(size_t)t2*EW + L];
        x2m = (L < 16) ? embW[(size_t)t2*EW + 64 + L] : 0.f;
    }
    const floatx4 zero4 = {};
    uint4 A0 = {}, A1 = {}, A2 = {};             // h_{-1} = 0

    for (int s = 0; s < Sn; ++s){
        // issue xp gather 3 ahead (consumed at s+3)
        int tok = sX[(s+3 < Sn) ? s+3 : Sn-1];
        float x1f = embW[(size_t)tok*EW + L];
        float x2f = (L < 16) ? embW[(size_t)tok*EW + 64 + L] : 0.f;

        half8 af0 = as_h8(A0), af1 = as_h8(A1), af2 = as_h8(A2);

        // y = W2 @ h : 5 output tiles x 3 K-steps
        floatx4 acc0, acc1, acc2, acc3, acc4;
        acc0 = __builtin_amdgcn_mfma_f32_16x16x32_f16(af0, bfr[0][0], zero4, 0,0,0);
        acc1 = __builtin_amdgcn_mfma_f32_16x16x32_f16(af0, bfr[1][0], zero4, 0,0,0);
        acc2 = __builtin_amdgcn_mfma_f32_16x16x32_f16(af0, bfr[2][0], zero4, 0,0,0);
        acc3 = __builtin_amdgcn_mfma_f32_16x16x32_f16(af0, bfr[3][0], zero4, 0,0,0);
        acc4 = __builtin_amdgcn_mfma_f32_16x16x32_f16(af0, bfr[4][0], zero4, 0,0,0);
        acc0 = __builtin_amdgcn_mfma_f32_16x16x32_f16(af1, bfr[0][1], acc0, 0,0,0);
        acc1 = __builtin_amdgcn_mfma_f32_16x16x32_f16(af1, bfr[1][1], acc1, 0,0,0);
        acc2 = __builtin_amdgcn_mfma_f32_16x16x32_f16(af1, bfr[2][1], acc2, 0,0,0);
        acc3 = __builtin_amdgcn_mfma_f32_16x16x32_f16(af1, bfr[3][1], acc3, 0,0,0);
        acc4 = __builtin_amdgcn_mfma_f32_16x16x32_f16(af1, bfr[4][1], acc4, 0,0,0);
        acc0 = __builtin_amdgcn_mfma_f32_16x16x32_f16(af2, bfr[0][2], acc0, 0,0,0);
        acc1 = __builtin_amdgcn_mfma_f32_16x16x32_f16(af2, bfr[1][2], acc1, 0,0,0);
        acc2 = __builtin_amdgcn_mfma_f32_16x16x32_f16(af2, bfr[2][2], acc2, 0,0,0);
        acc3 = __builtin_amdgcn_mfma_f32_16x16x32_f16(af2, bfr[3][2], acc3, 0,0,0);
        acc4 = __builtin_amdgcn_mfma_f32_16x16x32_f16(af2, bfr[4][2], acc4, 0,0,0);

        // lane-local extraction: y[L] = acc_g[0]; y[64+m] = acc4[0]
        float y1 = (L < 32) ? ((L < 16) ? acc0[0] : acc1[0])
                            : ((L < 48) ? acc2[0] : acc3[0]);
        float y2 = acc4[0];

        float h1 = sigmoidf(y1 + x1c);
        float h2 = sigmoidf(y2 + x2c);
        if (L >= 11) h2 = 0.f;                   // cols 75..79 pad -> 0
        ushort u1 = f2h(h1);
        ushort u2 = f2h(h2);
        hout[(size_t)s*KP + L] = u1;
        if (L < 16) hout[(size_t)s*KP + 64 + L] = u2;

        // pair adjacent lanes' f16 via DPP quad_perm [1,0,3,2] (even lanes valid)
        uint v1 = u1, v2 = u2;
        uint pr1 = (uint)__builtin_amdgcn_update_dpp(0, (int)v1, 0xB1, 0xF, 0xF, true);
        uint pr2 = (uint)__builtin_amdgcn_update_dpp(0, (int)v2, 0xB1, 0xF, 0xF, true);
        int q1 = (int)(v1 | (pr1 << 16));
        int q2 = (int)(v2 | (pr2 << 16));

        // rebuild A-fragments for step s+1: 12 independent bpermutes
        A0.x = (uint)__builtin_amdgcn_ds_bpermute(va0, q1);
        A0.y = (uint)__builtin_amdgcn_ds_bpermute(va1, q1);
        A0.z = (uint)__builtin_amdgcn_ds_bpermute(va2, q1);
        A0.w = (uint)__builtin_amdgcn_ds_bpermute(va3, q1);
        A1.x = (uint)__builtin_amdgcn_ds_bpermute(vb0, q1);
        A1.y = (uint)__builtin_amdgcn_ds_bpermute(vb1, q1);
        A1.z = (uint)__builtin_amdgcn_ds_bpermute(vb2, q1);
        A1.w = (uint)__builtin_amdgcn_ds_bpermute(vb3, q1);
        A2.x = (uint)__builtin_amdgcn_ds_bpermute(va0, q2);
        A2.y = (uint)__builtin_amdgcn_ds_bpermute(va1, q2);
        A2.z = (uint)__builtin_amdgcn_ds_bpermute(va2, q2);
        A2.w = (uint)__builtin_amdgcn_ds_bpermute(va3, q2);

        x1c = x1n; x2c = x2n; x1n = x1m; x2n = x2m; x1m = x1f; x2m = x2f;
    }
}

// ---------------------------------------------------------------------------
// Epilogue GEMM via MFMA 16x16x32 f16. Per block: 4 waves x 16 rows.
// Phase1: Z = H(16x96)@Wo^T + bo -> sigmoid -> O f16 in LDS (stride 104);
// Phase2: OUT = O@Wfc^T + bfc.
// C/D frag: col=lane&15, row=(lane>>4)*4+reg (m89-verified, dtype-indep).
// ---------------------------------------------------------------------------
__global__ __launch_bounds__(256) void k_out(
    const ushort* __restrict__ h_all, const ushort* __restrict__ woh,
    const ushort* __restrict__ wfh, const float* __restrict__ bo,
    const float* __restrict__ bfc, float* __restrict__ out)
{
    const int lane = threadIdx.x & 63;
    const int w    = threadIdx.x >> 6;
    const size_t r0 = (size_t)blockIdx.x*64 + w*16;
    const int m = lane & 15;
    const int g = lane >> 4;
    __shared__ __align__(16) ushort o_lds[4][16*104];
    ushort* ot = o_lds[w];
    // zero O pad cols 80..95 (read by k-step 2); wave-local, no barrier needed
    for (int i = lane; i < 128; i += 64){
        int row = i >> 3, cw = i & 7;
        *(uint*)&ot[row*104 + 80 + cw*2] = 0u;
    }
    // ---- Phase 1: Z = H @ Wo^T ----
    floatx4 acc1[5] = {};
    const ushort* hbase = h_all + r0*KP;
    #pragma unroll
    for (int ks = 0; ks < 3; ++ks){
        half8 a = *(const half8*)(hbase + (size_t)m*KP + ks*32 + g*8);
        #pragma unroll
        for (int t = 0; t < 5; ++t){
            half8 bt = *(const half8*)(woh + (16*t + m)*KP + ks*32 + g*8);
            acc1[t] = __builtin_amdgcn_mfma_f32_16x16x32_f16(a, bt, acc1[t], 0, 0, 0);
        }
    }
    // ---- bo + sigmoid -> O (f16, C layout) ----
    #pragma unroll
    for (int t = 0; t < 5; ++t){
        int n = 16*t + m;
        float bias = (n < Hn) ? bo[n] : 0.f;
        #pragma unroll
        for (int r = 0; r < 4; ++r){
            int row = g*4 + r;
            float o = 1.f/(1.f + __expf(-(acc1[t][r] + bias)));
            if (n >= Hn) o = 0.f;              // pad rows -> z=0 -> 0.5; kill
            ot[row*104 + n] = f2h(o);
        }
    }
    // wave-local LDS RAW: in-order DS pipe within a wave; no barrier
    // ---- Phase 2: OUT = O @ Wfc^T ----
    floatx4 acc2[8] = {};
    #pragma unroll
    for (int ks = 0; ks < 3; ++ks){
        half8 a = *(const half8*)(ot + m*104 + ks*32 + g*8);
        #pragma unroll
        for (int t = 0; t < 8; ++t){
            half8 bt = *(const half8*)(wfh + (16*t + m)*KP + ks*32 + g*8);
            acc2[t] = __builtin_amdgcn_mfma_f32_16x16x32_f16(a, bt, acc2[t], 0, 0, 0);
        }
    }
    // ---- bfc + store ----
    float* orow = out + r0*Ln;
    #pragma unroll
    for (int t = 0; t < 8; ++t){
        float bias = bfc[16*t + m];
        #pragma unroll
        for (int r = 0; r < 4; ++r){
            int row = g*4 + r;
            orow[(size_t)row*Ln + 16*t + m] = acc2[t][r] + bias;
        }
    }
}

extern "C" void kernel_launch(void* const* d_in, const int* in_sizes, int n_in,
                              void* d_out, int out_size, void* d_ws, size_t ws_size,
                              hipStream_t stream)
{
    const int*   X   = (const int*)d_in[0];
    const float* emb = (const float*)d_in[1];
    const float* W1  = (const float*)d_in[2];
    const float* b1  = (const float*)d_in[3];
    const float* W2  = (const float*)d_in[4];
    const float* b2  = (const float*)d_in[5];
    const float* Wo  = (const float*)d_in[6];
    const float* bo  = (const float*)d_in[7];
    const float* Wfc = (const float*)d_in[8];
    const float* bfc = (const float*)d_in[9];
    float* out = (float*)d_out;
    float* ws  = (float*)d_ws;

    float*  embW = ws + OFF_EMBW;
    ushort* hall = (ushort*)(ws + OFF_HALL);
    ushort* w2p  = (ushort*)(ws + OFF_W2P);
    ushort* woh  = (ushort*)(ws + OFF_WOH);
    ushort* wfh  = (ushort*)(ws + OFF_WFH);

    k_wprep<<<dim3(512), dim3(256), 0, stream>>>(W2, Wo, Wfc, w2p, woh, wfh, hall);
    k_embproj<<<dim3(Vn/64), dim3(64), 0, stream>>>(emb, W1, b1, b2, embW);
    k_rnn<<<dim3(Bn), dim3(64), 0, stream>>>(X, embW, w2p, hall);
    k_out<<<dim3((Bn*Sn)/64), dim3(256), 0, stream>>>(hall, woh, wfh, bo, bfc, out);
}

// Round 6
// 352.753 us; speedup vs baseline: 1.2810x; 1.0420x over previous
//
#include <hip/hip_runtime.h>
#include <hip/hip_bf16.h>

typedef unsigned int uint;
typedef unsigned short ushort;

constexpr int Bn = 256, Sn = 512, Vn = 32000, Dn = 100, Hn = 75, Ln = 128;
constexpr int EW = 80;    // embW row stride (floats), cols 75..79 zero
constexpr int KP = 96;    // h_all row stride (f16) = MFMA K-pad (3 x 32)
constexpr int W2S = 80;   // w2p row stride (f16)

// workspace layout (float units)
constexpr size_t OFF_EMBW = 0;                          // 32000*80   = 2,560,000 f
constexpr size_t OFF_HALL = OFF_EMBW + (size_t)Vn*EW;   // 131072*96 f16 = 6,291,456 f
constexpr size_t OFF_W2P  = OFF_HALL + (size_t)Bn*Sn*KP/2; // 80*80 f16 = 3200 f
constexpr size_t OFF_WOH  = OFF_W2P + 3200;             // 80*96 f16  = 3840 f
constexpr size_t OFF_WFH  = OFF_WOH + 3840;             // 128*96 f16 = 6144 f

typedef __attribute__((ext_vector_type(2))) _Float16 half2_t;
typedef __attribute__((ext_vector_type(8))) _Float16 half8;
typedef __attribute__((ext_vector_type(4))) float floatx4;

__device__ __forceinline__ ushort f2h(float f){
    union { _Float16 h; ushort u; } v; v.h = (_Float16)f; return v.u;
}
__device__ __forceinline__ half8 as_h8(uint4 u){
    union { uint4 u; half8 h; } v; v.u = u; return v.h;
}
__device__ __forceinline__ float sigmoidf(float z){
    return __builtin_amdgcn_rcpf(1.f + __expf(-z));
}

// ---------------------------------------------------------------------------
// Prep: W2 -> [80][80] f16 (pad 0), Wo -> [80][96] f16, Wfc -> [128][96] f16,
// zero h_all pad cols 80..95 (so k_out never reads garbage).
// ---------------------------------------------------------------------------
__global__ __launch_bounds__(256) void k_wprep(
    const float* __restrict__ W2, const float* __restrict__ Wo,
    const float* __restrict__ Wfc, ushort* __restrict__ w2p,
    ushort* __restrict__ woh, ushort* __restrict__ wfh, ushort* __restrict__ h_all)
{
    const int tid = blockIdx.x*256 + threadIdx.x;
    const int stride = gridDim.x*256;
    for (int i = tid; i < 80*W2S; i += stride){
        int r = i / W2S, k = i % W2S;
        w2p[i] = (r < Hn && k < Hn) ? f2h(W2[r*Hn + k]) : (ushort)0;
    }
    for (int i = tid; i < 80*KP; i += stride){
        int r = i / KP, k = i % KP;
        woh[i] = (r < Hn && k < Hn) ? f2h(Wo[r*Hn + k]) : (ushort)0;
    }
    for (int i = tid; i < Ln*KP; i += stride){
        int l = i / KP, k = i % KP;
        wfh[i] = (k < Hn) ? f2h(Wfc[l*Hn + k]) : (ushort)0;
    }
    // h_all[row][80..95] = 0  (8 uints per row)
    uint* hu = (uint*)h_all;
    for (int i = tid; i < Bn*Sn*8; i += stride){
        int row = i >> 3, c = i & 7;
        hu[(size_t)row*48 + 40 + c] = 0u;
    }
}

// ---------------------------------------------------------------------------
// embW[v][j] = sum_d emb[v][d]*W1[j][d] + b1[j] + b2[j], stride EW=80,
// cols 75..79 zero. One wave per 64 vocab rows.
// waves_per_eu(1,1): e[100] needs ~100 VGPRs; default occupancy heuristic
// would cap regs and spill e[] to scratch.
// ---------------------------------------------------------------------------
__global__ __attribute__((amdgpu_flat_work_group_size(64,64)))
__attribute__((amdgpu_waves_per_eu(1,1)))
void k_embproj(
    const float* __restrict__ emb, const float* __restrict__ W1,
    const float* __restrict__ b1, const float* __restrict__ b2,
    float* __restrict__ embW)
{
    const int lane = threadIdx.x;
    const int v = blockIdx.x*64 + lane;
    const float4* ev = (const float4*)(emb + (size_t)v*Dn);
    float e[Dn];
    #pragma unroll
    for (int q = 0; q < Dn/4; ++q){
        float4 x = ev[q];
        e[4*q] = x.x; e[4*q+1] = x.y; e[4*q+2] = x.z; e[4*q+3] = x.w;
    }
    __shared__ float s_out[64*EW];
    #pragma unroll 4
    for (int j = 0; j < Hn; ++j){
        float a0 = b1[j] + b2[j], a1 = 0.f, a2 = 0.f, a3 = 0.f;
        const float* w = W1 + j*Dn;              // uniform -> s_loads
        #pragma unroll
        for (int d = 0; d < Dn; d += 4){
            a0 += w[d]*e[d];     a1 += w[d+1]*e[d+1];
            a2 += w[d+2]*e[d+2]; a3 += w[d+3]*e[d+3];
        }
        s_out[lane*EW + j] = (a0+a1) + (a2+a3);
    }
    #pragma unroll
    for (int j = Hn; j < EW; ++j) s_out[lane*EW + j] = 0.f;
    __syncthreads();
    float* dst = embW + (size_t)blockIdx.x*64*EW;
    for (int i = lane; i < 64*EW; i += 64) dst[i] = s_out[i];
}

// ---------------------------------------------------------------------------
// Sequential scan: ONE WAVE per batch row. MFMA recurrence + bpermute
// h-broadcast (r5, 178us) + CHUNKED XP STAGING (r3-proven addressing).
// r5 post-mortem: removing the LDS h round-trip saved only ~25cy ->
// the ~500cy/step unexplained stall is the in-loop token-dependent embW
// gather: ds_read(sX) -> lgkmcnt -> VMEM gather (L3/HBM ~600-900cy) ->
// vmcnt, interleaved with bpermute lgkm + store vmcnt -> the 3-deep
// rotation collapses. Fix: take the gather OFF the per-step chain --
// stage xp for 64 steps into an LDS double buffer via 20 global_load_lds
// (width 16; global src per-lane so token gather is legal; LDS dst linear).
// ONE vmcnt drain (__syncthreads) per 64 steps; in-loop xp is affine
// ds_read_b32, 2-deep register prefetch (counted lgkmcnt; m97 evidence:
// hipcc does NOT insert per-ds_read vmcnt alias drains, only at barriers).
// Weights stay MFMA B-frags in regs (60 VGPR); h-broadcast stays bpermute.
// ---------------------------------------------------------------------------
__global__ __attribute__((amdgpu_flat_work_group_size(64,64)))
__attribute__((amdgpu_waves_per_eu(1,1)))
void k_rnn(
    const int* __restrict__ X, const float* __restrict__ embW,
    const ushort* __restrict__ w2p, ushort* __restrict__ h_all)
{
    const int b = blockIdx.x;
    const int L = threadIdx.x;
    const int m = L & 15;
    const int g = L >> 4;
    __shared__ int sX[Sn];                         // 2 KB
    __shared__ __align__(16) float xpb[2][64*80];  // 40 KB xp double buffer

    for (int i = L; i < Sn; i += 64) sX[i] = X[b*Sn + i];

    // B-fragments: lane holds W2[n=16t+m][k0..k0+7], k0 = ks*32+g*8.
    half8 bfr[5][3];
    #pragma unroll
    for (int t = 0; t < 5; ++t){
        #pragma unroll
        for (int ks = 0; ks < 3; ++ks){
            int k0 = ks*32 + g*8;
            half8 bv = {};
            if (k0 < 80) bv = *(const half8*)(w2p + (size_t)(16*t + m)*W2S + k0);
            bfr[t][ks] = bv;                     // k0>=80: A is zero there anyway
        }
    }
    __syncthreads();

    // stage chunk c (64 steps x 320B) into xpb[c&1] via global_load_lds.
    // idx = k*64+L; row cs = idx/20, off = idx%20; src 16B-aligned;
    // LDS dst = wave-uniform base + lane*16 (r3-verified correct).
    auto stage = [&](int c){
        float* buf = xpb[c & 1];
        const int base = c*64;
        #pragma unroll
        for (int k = 0; k < 20; ++k){
            int idx = k*64 + L;
            int cs  = idx / 20;
            int off = idx - cs*20;
            int tok = sX[base + cs];
            const float* src = embW + (size_t)tok*EW + off*4;
            __builtin_amdgcn_global_load_lds(
                (const __attribute__((address_space(1))) uint*)src,
                (__attribute__((address_space(3))) uint*)(buf + k*256),
                16, 0, 0);
        }
    };

    // bpermute byte-addresses (loop-invariant):
    // af0/af2 pair j <- src lane 2*(4g+j)  -> addr 32g+8j; af1: +128B
    int va0 = 32*g,      va1 = 32*g + 8,  va2 = 32*g + 16, va3 = 32*g + 24;
    int vb0 = va0 + 128, vb1 = va1 + 128, vb2 = va2 + 128, vb3 = va3 + 128;

    ushort* hout = h_all + (size_t)b*Sn*KP;
    const floatx4 zero4 = {};
    uint4 A0 = {}, A1 = {}, A2 = {};             // h_{-1} = 0

    stage(0);
    for (int c = 0; c < 8; ++c){
        __syncthreads();                 // chunk c landed (vmcnt drain, 1/64 steps)
        if (c < 7) stage(c + 1);         // async stage into the other buffer
        const float* xp = xpb[c & 1];
        // xp prefetch pipeline (2 deep), affine LDS addresses
        float x1c = xp[L];
        float x2c = (L < 16) ? xp[64 + L] : 0.f;
        float x1n = xp[80 + L];
        float x2n = (L < 16) ? xp[80 + 64 + L] : 0.f;
        for (int t = 0; t < 64; ++t){
            int pf = (t + 2 < 64) ? t + 2 : 63;    // clamped slots never consumed
            float x1f = xp[pf*80 + L];
            float x2f = (L < 16) ? xp[pf*80 + 64 + L] : 0.f;

            half8 af0 = as_h8(A0), af1 = as_h8(A1), af2 = as_h8(A2);

            // y = W2 @ h : 5 output tiles x 3 K-steps
            floatx4 acc0, acc1, acc2, acc3, acc4;
            acc0 = __builtin_amdgcn_mfma_f32_16x16x32_f16(af0, bfr[0][0], zero4, 0,0,0);
            acc1 = __builtin_amdgcn_mfma_f32_16x16x32_f16(af0, bfr[1][0], zero4, 0,0,0);
            acc2 = __builtin_amdgcn_mfma_f32_16x16x32_f16(af0, bfr[2][0], zero4, 0,0,0);
            acc3 = __builtin_amdgcn_mfma_f32_16x16x32_f16(af0, bfr[3][0], zero4, 0,0,0);
            acc4 = __builtin_amdgcn_mfma_f32_16x16x32_f16(af0, bfr[4][0], zero4, 0,0,0);
            acc0 = __builtin_amdgcn_mfma_f32_16x16x32_f16(af1, bfr[0][1], acc0, 0,0,0);
            acc1 = __builtin_amdgcn_mfma_f32_16x16x32_f16(af1, bfr[1][1], acc1, 0,0,0);
            acc2 = __builtin_amdgcn_mfma_f32_16x16x32_f16(af1, bfr[2][1], acc2, 0,0,0);
            acc3 = __builtin_amdgcn_mfma_f32_16x16x32_f16(af1, bfr[3][1], acc3, 0,0,0);
            acc4 = __builtin_amdgcn_mfma_f32_16x16x32_f16(af1, bfr[4][1], acc4, 0,0,0);
            acc0 = __builtin_amdgcn_mfma_f32_16x16x32_f16(af2, bfr[0][2], acc0, 0,0,0);
            acc1 = __builtin_amdgcn_mfma_f32_16x16x32_f16(af2, bfr[1][2], acc1, 0,0,0);
            acc2 = __builtin_amdgcn_mfma_f32_16x16x32_f16(af2, bfr[2][2], acc2, 0,0,0);
            acc3 = __builtin_amdgcn_mfma_f32_16x16x32_f16(af2, bfr[3][2], acc3, 0,0,0);
            acc4 = __builtin_amdgcn_mfma_f32_16x16x32_f16(af2, bfr[4][2], acc4, 0,0,0);

            // lane-local extraction: y[L] = acc_g[0]; y[64+m] = acc4[0]
            float y1 = (L < 32) ? ((L < 16) ? acc0[0] : acc1[0])
                                : ((L < 48) ? acc2[0] : acc3[0]);
            float y2 = acc4[0];

            float h1 = sigmoidf(y1 + x1c);
            float h2 = sigmoidf(y2 + x2c);
            if (L >= 11) h2 = 0.f;                 // cols 75..79 pad -> 0
            ushort u1 = f2h(h1);
            ushort u2 = f2h(h2);
            int s = c*64 + t;
            hout[(size_t)s*KP + L] = u1;
            if (L < 16) hout[(size_t)s*KP + 64 + L] = u2;

            // pair adjacent lanes' f16 via DPP quad_perm [1,0,3,2] (even lanes)
            uint v1 = u1, v2 = u2;
            uint pr1 = (uint)__builtin_amdgcn_update_dpp(0, (int)v1, 0xB1, 0xF, 0xF, true);
            uint pr2 = (uint)__builtin_amdgcn_update_dpp(0, (int)v2, 0xB1, 0xF, 0xF, true);
            int q1 = (int)(v1 | (pr1 << 16));
            int q2 = (int)(v2 | (pr2 << 16));

            // rebuild A-fragments for step s+1: 12 independent bpermutes
            A0.x = (uint)__builtin_amdgcn_ds_bpermute(va0, q1);
            A0.y = (uint)__builtin_amdgcn_ds_bpermute(va1, q1);
            A0.z = (uint)__builtin_amdgcn_ds_bpermute(va2, q1);
            A0.w = (uint)__builtin_amdgcn_ds_bpermute(va3, q1);
            A1.x = (uint)__builtin_amdgcn_ds_bpermute(vb0, q1);
            A1.y = (uint)__builtin_amdgcn_ds_bpermute(vb1, q1);
            A1.z = (uint)__builtin_amdgcn_ds_bpermute(vb2, q1);
            A1.w = (uint)__builtin_amdgcn_ds_bpermute(vb3, q1);
            A2.x = (uint)__builtin_amdgcn_ds_bpermute(va0, q2);
            A2.y = (uint)__builtin_amdgcn_ds_bpermute(va1, q2);
            A2.z = (uint)__builtin_amdgcn_ds_bpermute(va2, q2);
            A2.w = (uint)__builtin_amdgcn_ds_bpermute(va3, q2);

            x1c = x1n; x2c = x2n; x1n = x1f; x2n = x2f;
        }
    }
}

// ---------------------------------------------------------------------------
// Epilogue GEMM via MFMA 16x16x32 f16. Per block: 4 waves x 16 rows.
// Phase1: Z = H(16x96)@Wo^T + bo -> sigmoid -> O f16 in LDS (stride 104);
// Phase2: OUT = O@Wfc^T + bfc.
// C/D frag: col=lane&15, row=(lane>>4)*4+reg (m89-verified, dtype-indep).
// ---------------------------------------------------------------------------
__global__ __launch_bounds__(256) void k_out(
    const ushort* __restrict__ h_all, const ushort* __restrict__ woh,
    const ushort* __restrict__ wfh, const float* __restrict__ bo,
    const float* __restrict__ bfc, float* __restrict__ out)
{
    const int lane = threadIdx.x & 63;
    const int w    = threadIdx.x >> 6;
    const size_t r0 = (size_t)blockIdx.x*64 + w*16;
    const int m = lane & 15;
    const int g = lane >> 4;
    __shared__ __align__(16) ushort o_lds[4][16*104];
    ushort* ot = o_lds[w];
    // zero O pad cols 80..95 (read by k-step 2); wave-local, no barrier needed
    for (int i = lane; i < 128; i += 64){
        int row = i >> 3, cw = i & 7;
        *(uint*)&ot[row*104 + 80 + cw*2] = 0u;
    }
    // ---- Phase 1: Z = H @ Wo^T ----
    floatx4 acc1[5] = {};
    const ushort* hbase = h_all + r0*KP;
    #pragma unroll
    for (int ks = 0; ks < 3; ++ks){
        half8 a = *(const half8*)(hbase + (size_t)m*KP + ks*32 + g*8);
        #pragma unroll
        for (int t = 0; t < 5; ++t){
            half8 bt = *(const half8*)(woh + (16*t + m)*KP + ks*32 + g*8);
            acc1[t] = __builtin_amdgcn_mfma_f32_16x16x32_f16(a, bt, acc1[t], 0, 0, 0);
        }
    }
    // ---- bo + sigmoid -> O (f16, C layout) ----
    #pragma unroll
    for (int t = 0; t < 5; ++t){
        int n = 16*t + m;
        float bias = (n < Hn) ? bo[n] : 0.f;
        #pragma unroll
        for (int r = 0; r < 4; ++r){
            int row = g*4 + r;
            float o = 1.f/(1.f + __expf(-(acc1[t][r] + bias)));
            if (n >= Hn) o = 0.f;              // pad rows -> z=0 -> 0.5; kill
            ot[row*104 + n] = f2h(o);
        }
    }
    // wave-local LDS RAW: in-order DS pipe within a wave; no barrier
    // ---- Phase 2: OUT = O @ Wfc^T ----
    floatx4 acc2[8] = {};
    #pragma unroll
    for (int ks = 0; ks < 3; ++ks){
        half8 a = *(const half8*)(ot + m*104 + ks*32 + g*8);
        #pragma unroll
        for (int t = 0; t < 8; ++t){
            half8 bt = *(const half8*)(wfh + (16*t + m)*KP + ks*32 + g*8);
            acc2[t] = __builtin_amdgcn_mfma_f32_16x16x32_f16(a, bt, acc2[t], 0, 0, 0);
        }
    }
    // ---- bfc + store ----
    float* orow = out + r0*Ln;
    #pragma unroll
    for (int t = 0; t < 8; ++t){
        float bias = bfc[16*t + m];
        #pragma unroll
        for (int r = 0; r < 4; ++r){
            int row = g*4 + r;
            orow[(size_t)row*Ln + 16*t + m] = acc2[t][r] + bias;
        }
    }
}

extern "C" void kernel_launch(void* const* d_in, const int* in_sizes, int n_in,
                              void* d_out, int out_size, void* d_ws, size_t ws_size,
                              hipStream_t stream)
{
    const int*   X   = (const int*)d_in[0];
    const float* emb = (const float*)d_in[1];
    const float* W1  = (const float*)d_in[2];
    const float* b1  = (const float*)d_in[3];
    const float* W2  = (const float*)d_in[4];
    const float* b2  = (const float*)d_in[5];
    const float* Wo  = (const float*)d_in[6];
    const float* bo  = (const float*)d_in[7];
    const float* Wfc = (const float*)d_in[8];
    const float* bfc = (const float*)d_in[9];
    float* out = (float*)d_out;
    float* ws  = (float*)d_ws;

    float*  embW = ws + OFF_EMBW;
    ushort* hall = (ushort*)(ws + OFF_HALL);
    ushort* w2p  = (ushort*)(ws + OFF_W2P);
    ushort* woh  = (ushort*)(ws + OFF_WOH);
    ushort* wfh  = (ushort*)(ws + OFF_WFH);

    k_wprep<<<dim3(512), dim3(256), 0, stream>>>(W2, Wo, Wfc, w2p, woh, wfh, hall);
    k_embproj<<<dim3(Vn/64), dim3(64), 0, stream>>>(emb, W1, b1, b2, embW);
    k_rnn<<<dim3(Bn), dim3(64), 0, stream>>>(X, embW, w2p, hall);
    k_out<<<dim3((Bn*Sn)/64), dim3(256), 0, stream>>>(hall, woh, wfh, bo, bfc, out);
}